// Round 6
// baseline (298.596 us; speedup 1.0000x reference)
//
#include <hip/hip_runtime.h>
#include <math.h>

// NoisyTopkRouter: B=8,T=4096,NE=1024,E=16,TOPK=2,LIN=1824
// tokens = 32768; streamed features = 1792 (city-32 folded into a constant)
// out = [router 32768*16][indices 32768*2][gate1 32768*16] all f32
//
// R10: kill the drain-to-0 convoy. R4(reg-staged,1blk) and R9(DMA,2blk) both
// hit the SAME ~9.9Kcy/chunk wall: prefetch depth 1 + vmcnt(0)+barrier per
// chunk -> whole chip dumps ~12MB of barrier-synced requests, every CU waits
// for its slowest line, memory idles during compute (3TB/s agg, HBM 1TB/s).
// T3/T4 fix: D=3 ring, counted vmcnt(3) (one full chunk stays in flight
// across the barrier; vmcnt(0) ONLY at last iter), RAW s_barrier (NOT
// __syncthreads, which force-emits vmcnt(0) -- R9's hidden serializer) +
// sched_barrier(0) fence (rule #18).
// Geometry: TOKS=128, 1024 thr (16 waves = 4/SIMD), grid 256 = 1 block/CU.
// LDS = 3*(A 32KB + W 8KB) = 120KB. 16-way split-K (4-k slab/wave), lane =
// 8tok x 8e: 256 fmac / 16 ds_read_b128 per chunk. acc 64 VGPR + 8 W-frags.
// DMA: uniform 3 instr/wave/chunk (A:2 all-lane, W:1 lanes<32) -> vmcnt
// counts are per-wave-exact. Swizzle per rule #21: linear LDS dest, source
// col c4^(r&15), read col w^tg (2-way banks, free m136).

#define TOKS 128
#define NCHUNK 28
#define I_OFF 524288        // 32768*16
#define G_OFF 589824        // 524288 + 32768*2
#define SS 36               // score-row stride (reduction scratch)

__device__ __forceinline__ float softplus_f(float x) {
  // jax.nn.softplus = max(x,0) + log1p(exp(-|x|))
  return fmaxf(x, 0.0f) + log1pf(expf(-fabsf(x)));
}

#define FMA8(s, wa, wb, j)                         \
  accL[j].x = fmaf(s, wa.x, accL[j].x);            \
  accL[j].y = fmaf(s, wa.y, accL[j].y);            \
  accL[j].z = fmaf(s, wa.z, accL[j].z);            \
  accL[j].w = fmaf(s, wa.w, accL[j].w);            \
  accH[j].x = fmaf(s, wb.x, accH[j].x);            \
  accH[j].y = fmaf(s, wb.y, accH[j].y);            \
  accH[j].z = fmaf(s, wb.z, accH[j].z);            \
  accH[j].w = fmaf(s, wb.w, accH[j].w);

__device__ __forceinline__ void dma16(const float* g, float* l) {
  __builtin_amdgcn_global_load_lds(
      (const __attribute__((address_space(1))) void*)g,
      (__attribute__((address_space(3))) void*)l, 16, 0, 0);
}

__global__ __launch_bounds__(1024, 1) void router_kernel(
    const float* __restrict__ mh, const float* __restrict__ dt,
    const float* __restrict__ dd, const float* __restrict__ rg,
    const float* __restrict__ de, const float* __restrict__ cemb_all,
    const float* __restrict__ w_route, const float* __restrict__ b_route,
    const float* __restrict__ w_noise, const float* __restrict__ b_noise,
    const float* __restrict__ eps, const int* __restrict__ city_index,
    float* __restrict__ out) {
  // ring: A0 @0 | A1 @8192 | A2 @16384 | W0 @24576 | W1 @26624 | W2 @28672
  // post-loop overlay: sS0 [128][36] @0 (A0), sS1 @8192 (A1), city @16384
  __shared__ float smem[30720];   // 122880 B -> 1 block/CU, 16 waves

  const int tid = threadIdx.x;
  const int w   = tid >> 6;        // wave 0..15: k-slab [w*4, w*4+4) of chunk
  const int ln  = tid & 63;
  const int tg  = ln & 15;         // tokens {tg + 16j}, j=0..7
  const int eg  = ln >> 4;         // e-cols eg*8..eg*8+7 (of 32 = route|noise)
  const int blockTok = blockIdx.x * TOKS;

  float4 accL[8], accH[8];
#pragma unroll
  for (int j = 0; j < 8; ++j) {
    accL[j] = make_float4(0.f, 0.f, 0.f, 0.f);
    accH[j] = make_float4(0.f, 0.f, 0.f, 0.f);
  }

  auto a_src = [&](int g, int row) -> const float* {
    const float* base; int stride;
    if (g < 16)      { base = mh + g * 64;        stride = 1024; }
    else if (g < 20) { base = dt + (g - 16) * 64; stride = 256; }
    else if (g < 24) { base = dd + (g - 20) * 64; stride = 256; }
    else             { base = (g < 26) ? rg + (g - 24) * 64
                                       : de + (g - 26) * 64;
                       stride = 128; }
    return base + (size_t)(blockTok + row) * stride;
  };

  // One chunk: A 2048 f4 slots (2/thread), W 512 f4 (1 per wave, lanes<32).
  // Uniform 3 DMA instrs per wave. A source col swizzled: LDS slot (r,p)
  // holds global f4-col p^(r&15) (inside the row's 256B segment: coalesced).
  auto stage = [&](int g, float* Ab, float* Wb) {
#pragma unroll
    for (int i = 0; i < 2; ++i) {
      const int slot = i * 1024 + tid;
      const int r    = slot >> 4;                 // token row 0..127
      const int c4   = (slot & 15) ^ (r & 15);    // swizzled source col
      dma16(a_src(g, r) + c4 * 4, Ab + slot * 4);
    }
    if (ln < 32) {                                // 1 instr/wave, exec=lo32
      const int slot = w * 32 + ln;               // W f4-slot 0..511
      const int kr   = slot >> 3;                 // k-row 0..63
      const int c4   = slot & 7;                  // 8 f4 per row (32 e)
      const int kb   = g * 64 + ((g >= 16) ? 32 : 0) + kr;  // skip city rows
      const float* ws = (c4 < 4) ? (w_route + kb * 16 + c4 * 4)
                                 : (w_noise + kb * 16 + (c4 - 4) * 4);
      dma16(ws, Wb + slot * 4);
    }
  };

  float* Ac = smem;          float* Wc = smem + 24576;
  float* An = smem +  8192;  float* Wn = smem + 26624;
  float* A3 = smem + 16384;  float* W3 = smem + 28672;

  stage(0, Ac, Wc);
  stage(1, An, Wn);

  const int s4  = w * 4;               // this wave's k-rows in the chunk
  const int px4 = (w ^ tg) * 4;        // swizzled A read col (f4 slot w)

  for (int c = 0; c < NCHUNK; ++c) {
    // counted wait: own 3 loads of chunk c landed; chunk c+1 stays in
    // flight. Raw barrier publishes cross-wave. NEVER __syncthreads here.
    if (c == NCHUNK - 1) asm volatile("s_waitcnt vmcnt(0)" ::: "memory");
    else                 asm volatile("s_waitcnt vmcnt(3)" ::: "memory");
    __builtin_amdgcn_s_barrier();
    __builtin_amdgcn_sched_barrier(0);   // nothing crosses the barrier

    if (c + 2 < NCHUNK) stage(c + 2, A3, W3);  // into buffer freed at c-1

    // 8 W-fragments for this wave's 4 k-rows (bcast reads, conflict-free)
    const float4 wa0 = *(const float4*)&Wc[(s4 + 0) * 32 + eg * 8];
    const float4 wb0 = *(const float4*)&Wc[(s4 + 0) * 32 + eg * 8 + 4];
    const float4 wa1 = *(const float4*)&Wc[(s4 + 1) * 32 + eg * 8];
    const float4 wb1 = *(const float4*)&Wc[(s4 + 1) * 32 + eg * 8 + 4];
    const float4 wa2 = *(const float4*)&Wc[(s4 + 2) * 32 + eg * 8];
    const float4 wb2 = *(const float4*)&Wc[(s4 + 2) * 32 + eg * 8 + 4];
    const float4 wa3 = *(const float4*)&Wc[(s4 + 3) * 32 + eg * 8];
    const float4 wb3 = *(const float4*)&Wc[(s4 + 3) * 32 + eg * 8 + 4];

#pragma unroll
    for (int j = 0; j < 8; ++j) {
      const float4 a = *(const float4*)&Ac[(tg + 16 * j) * 64 + px4];
      FMA8(a.x, wa0, wb0, j);
      FMA8(a.y, wa1, wb1, j);
      FMA8(a.z, wa2, wb2, j);
      FMA8(a.w, wa3, wb3, j);
    }

    float* t;
    t = Ac; Ac = An; An = A3; A3 = t;
    t = Wc; Wc = Wn; Wn = W3; W3 = t;
  }

  __syncthreads();   // main loop fully done (vmcnt already 0 at c=27)

  // ---- city constants into dead A2 region (consumed by epilogue) ----
  float* sS0   = smem;           // waves 0..7 partials  [128][36]
  float* sS1   = smem + 8192;    // waves 8..15 partials [128][36]
  float* cityL = smem + 16384;
  if (tid < 32) {
    const int e = tid & 15;
    const float* wsrc = (tid < 16) ? w_route : w_noise;
    const float* bsrc = (tid < 16) ? b_route : b_noise;
    const float* ce = cemb_all + city_index[0] * 32;
    float sacc = bsrc[e];
#pragma unroll
    for (int j = 0; j < 32; ++j)
      sacc = fmaf(ce[j], wsrc[(1024 + j) * 16 + e], sacc);
    cityL[tid] = sacc;
  }

  // ---- 16-way split-K: two parallel 8-round serial-RMW chains ----
  for (int r = 0; r < 8; ++r) {
    if ((w & 7) == r) {
      float* S = (w < 8) ? sS0 : sS1;
#pragma unroll
      for (int j = 0; j < 8; ++j) {
        float* p = &S[(tg + 16 * j) * SS + eg * 8];
        if (r == 0) {
          *(float4*)(p)     = accL[j];
          *(float4*)(p + 4) = accH[j];
        } else {
          float4 x0 = *(float4*)(p), x1 = *(float4*)(p + 4);
          x0.x += accL[j].x; x0.y += accL[j].y; x0.z += accL[j].z; x0.w += accL[j].w;
          x1.x += accH[j].x; x1.y += accH[j].y; x1.z += accH[j].z; x1.w += accH[j].w;
          *(float4*)(p)     = x0;
          *(float4*)(p + 4) = x1;
        }
      }
    }
    __syncthreads();
  }

  // ---- epilogue: one lane per token ----
  if (tid < TOKS) {
    const int tokg = blockTok + tid;
    float l[32];
#pragma unroll
    for (int e4 = 0; e4 < 8; ++e4) {
      float4 s0 = *(const float4*)&sS0[tid * SS + e4 * 4];
      float4 s1 = *(const float4*)&sS1[tid * SS + e4 * 4];
      l[e4 * 4 + 0] = s0.x + s1.x;
      l[e4 * 4 + 1] = s0.y + s1.y;
      l[e4 * 4 + 2] = s0.z + s1.z;
      l[e4 * 4 + 3] = s0.w + s1.w;
    }
#pragma unroll
    for (int e = 0; e < 32; ++e) l[e] += cityL[e];

    const float* ep = eps + (size_t)tokg * 16;
    float n[16];
#pragma unroll
    for (int e = 0; e < 16; ++e)
      n[e] = fmaf(ep[e], softplus_f(l[16 + e]), l[e]);

    // top-2, lowest-index tie-break (matches lax.top_k)
    float m1 = -INFINITY; int i1 = 0;
#pragma unroll
    for (int e = 0; e < 16; ++e)
      if (n[e] > m1) { m1 = n[e]; i1 = e; }
    float m2 = -INFINITY; int i2 = 0;
#pragma unroll
    for (int e = 0; e < 16; ++e)
      if (e != i1 && n[e] > m2) { m2 = n[e]; i2 = e; }

    float ex[16], Z = 0.f;
#pragma unroll
    for (int e = 0; e < 16; ++e) { ex[e] = expf(n[e] - m1); Z += ex[e]; }
    const float invZ  = 1.0f / Z;
    const float invZ2 = 1.0f / (1.0f + expf(m2 - m1));  // ex[i1]=1

    float r[16], g1[16];
#pragma unroll
    for (int e = 0; e < 16; ++e) {
      r[e]  = (e == i1 || e == i2) ? ex[e] * invZ2 : 0.0f;
      g1[e] = ex[e] * invZ;
    }

    float* ro = out + (size_t)tokg * 16;
#pragma unroll
    for (int e4 = 0; e4 < 4; ++e4)
      *(float4*)(ro + e4 * 4) = make_float4(r[e4*4], r[e4*4+1], r[e4*4+2], r[e4*4+3]);

    out[I_OFF + (size_t)tokg * 2 + 0] = (float)i1;
    out[I_OFF + (size_t)tokg * 2 + 1] = (float)i2;

    float* go = out + G_OFF + (size_t)tokg * 16;
#pragma unroll
    for (int e4 = 0; e4 < 4; ++e4)
      *(float4*)(go + e4 * 4) = make_float4(g1[e4*4], g1[e4*4+1], g1[e4*4+2], g1[e4*4+3]);
  }
}

extern "C" void kernel_launch(void* const* d_in, const int* in_sizes, int n_in,
                              void* d_out, int out_size, void* d_ws, size_t ws_size,
                              hipStream_t stream) {
  const float* mh = (const float*)d_in[0];   // [8,4096,1024]
  const float* dt = (const float*)d_in[1];   // [8,4096,256]
  const float* dd = (const float*)d_in[2];   // [8,4096,256]
  const float* rg = (const float*)d_in[3];   // [8,4096,128]
  const float* de = (const float*)d_in[4];   // [8,4096,128]
  const float* ce = (const float*)d_in[5];   // [4,32]
  const float* wr = (const float*)d_in[6];   // [1824,16]
  const float* br = (const float*)d_in[7];   // [16]
  const float* wn = (const float*)d_in[8];   // [1824,16]
  const float* bn = (const float*)d_in[9];   // [16]
  const float* ep = (const float*)d_in[10];  // [8,4096,16]
  const int*   ci = (const int*)d_in[11];    // scalar
  float* out = (float*)d_out;

  router_kernel<<<256, 1024, 0, stream>>>(mh, dt, dd, rg, de, ce, wr, br, wn, bn,
                                          ep, ci, out);
}